// Round 1
// baseline (20801.768 us; speedup 1.0000x reference)
//
#include <hip/hip_runtime.h>
#include <hip/hip_bf16.h>
#include <cstdint>

#define N_NODES 20000
#define N_EDGES 100000
#define WALK 4
#define FDIM 256
#define HID 64
#define NHEAD 8
#define HR 512
#define G3 1536
#define OUTD 16

__device__ __forceinline__ float b2f(unsigned short u){
  union{float f; unsigned u;} x; x.u = ((unsigned)u)<<16; return x.f;
}
__device__ __forceinline__ unsigned short f2b(float f){
  union{float f; unsigned u;} x; x.f = f;
  unsigned r = x.u + 0x7FFFu + ((x.u>>16)&1u);
  return (unsigned short)(r>>16);
}
__device__ __forceinline__ float sigmoidf_(float v){ return 1.0f/(1.0f+__expf(-v)); }

// ---------------- emb = x @ W_mlp.T + b_mlp  (20000x64) ----------------
__launch_bounds__(256)
__global__ void emb_kernel(const float* __restrict__ x,
                           const float* __restrict__ Wm,
                           const float* __restrict__ bm,
                           float* __restrict__ emb)
{
  __shared__ float xs[4][FDIM];
  const int tid = threadIdx.x;
  const int node0 = blockIdx.x * 4;
  {
    const int row = tid >> 6;         // 0..3
    const int k4  = (tid & 63) * 4;   // 0..252
    *reinterpret_cast<float4*>(&xs[row][k4]) =
      *reinterpret_cast<const float4*>(&x[(size_t)(node0+row)*FDIM + k4]);
  }
  __syncthreads();
  const int nn = tid >> 6, c = tid & 63;
  float acc = bm[c];
  const float* wr = &Wm[c*FDIM];
  #pragma unroll 8
  for (int k=0;k<FDIM;k+=4){
    const float4 w = *reinterpret_cast<const float4*>(&wr[k]);
    acc += xs[nn][k]*w.x + xs[nn][k+1]*w.y + xs[nn][k+2]*w.z + xs[nn][k+3]*w.w;
  }
  emb[(size_t)(node0+nn)*HID + c] = acc;
}

// ---------------- one GRU step (tiled f32 GEMM, fused gates) ----------------
// block: 256 thr; tile: 32 edges x 64 d-cols (x3 gates); K chunks of 32.
template<bool FIRST>
__launch_bounds__(256)
__global__ void gru_kernel(const float* __restrict__ emb,
                           const int* __restrict__ idx,
                           const unsigned short* __restrict__ h_in,
                           unsigned short* __restrict__ h_out,
                           const float* __restrict__ W_ih,
                           const float* __restrict__ W_hh,
                           const float* __restrict__ b_ih,
                           const float* __restrict__ b_hh,
                           int step)
{
  __shared__ float As[32][36];     // [edge][k]  (pad: 144B rows, 16B aligned)
  __shared__ float Bs[32][200];    // [k][r], r = grp*64 + d_local (800B rows)
  const int tid = threadIdx.x;
  const int tx = tid & 15, ty = tid >> 4;
  const int e0 = blockIdx.x * 32;
  const int d0 = blockIdx.y * 64;

  float accR[2][4]={{0.f}}, accZ[2][4]={{0.f}}, accXN[2][4]={{0.f}}, accHN[2][4]={{0.f}};

  auto loadB = [&](const float* __restrict__ W, int ldw, int k0){
    #pragma unroll
    for (int it=0; it<6; ++it){
      const int flat = it*256 + tid;     // [0,1536) float4 units
      const int r  = flat % 192;
      const int kc = flat / 192;         // 0..7
      const int g  = (r>>6)*HR + d0 + (r&63);
      const float4 w = *reinterpret_cast<const float4*>(&W[(size_t)g*ldw + k0 + kc*4]);
      Bs[kc*4+0][r] = w.x;
      Bs[kc*4+1][r] = w.y;
      Bs[kc*4+2][r] = w.z;
      Bs[kc*4+3][r] = w.w;
    }
  };

  auto compute = [&](float (&accN)[2][4]){
    #pragma unroll
    for (int kq=0; kq<32; kq+=4){
      const float4 a0 = *reinterpret_cast<const float4*>(&As[ty*2+0][kq]);
      const float4 a1 = *reinterpret_cast<const float4*>(&As[ty*2+1][kq]);
      const float ae[2][4] = {{a0.x,a0.y,a0.z,a0.w},{a1.x,a1.y,a1.z,a1.w}};
      #pragma unroll
      for (int j=0;j<4;++j){
        const int k = kq+j;
        const float4 br = *reinterpret_cast<const float4*>(&Bs[k][tx*4]);
        const float4 bz = *reinterpret_cast<const float4*>(&Bs[k][64+tx*4]);
        const float4 bn = *reinterpret_cast<const float4*>(&Bs[k][128+tx*4]);
        #pragma unroll
        for (int e=0;e<2;++e){
          const float a = ae[e][j];
          accR[e][0]+=a*br.x; accR[e][1]+=a*br.y; accR[e][2]+=a*br.z; accR[e][3]+=a*br.w;
          accZ[e][0]+=a*bz.x; accZ[e][1]+=a*bz.y; accZ[e][2]+=a*bz.z; accZ[e][3]+=a*bz.w;
          accN[e][0]+=a*bn.x; accN[e][1]+=a*bn.y; accN[e][2]+=a*bn.z; accN[e][3]+=a*bn.w;
        }
      }
    }
  };

  const int e_l = tid >> 3;            // 0..31
  const int k4  = (tid & 7) * 4;       // 0..28
  const int node = idx[(e0 + e_l)*WALK + step];

  // ---- x phase: K=64 from gathered emb ----
  #pragma unroll
  for (int k0=0; k0<HID; k0+=32){
    __syncthreads();
    *reinterpret_cast<float4*>(&As[e_l][k4]) =
      *reinterpret_cast<const float4*>(&emb[(size_t)node*HID + k0 + k4]);
    loadB(W_ih, HID, k0);
    __syncthreads();
    compute(accXN);
  }

  // ---- h phase: K=512 from h_in (bf16) ----
  if (!FIRST){
    for (int k0=0; k0<HR; k0+=32){
      __syncthreads();
      {
        const ushort4 v = *reinterpret_cast<const ushort4*>(&h_in[(size_t)(e0+e_l)*HR + k0 + k4]);
        As[e_l][k4+0] = b2f(v.x);
        As[e_l][k4+1] = b2f(v.y);
        As[e_l][k4+2] = b2f(v.z);
        As[e_l][k4+3] = b2f(v.w);
      }
      loadB(W_hh, HR, k0);
      __syncthreads();
      compute(accHN);
    }
  }

  // ---- epilogue: gate nonlinearities + h update ----
  #pragma unroll
  for (int e=0;e<2;++e){
    const int eg = e0 + ty*2 + e;
    ushort4 hv;
    unsigned short* hvp = reinterpret_cast<unsigned short*>(&hv);
    #pragma unroll
    for (int dq=0;dq<4;++dq){
      const int d = d0 + tx*4 + dq;
      const float r = sigmoidf_(accR[e][dq] + b_ih[d] + b_hh[d]);
      const float z = sigmoidf_(accZ[e][dq] + b_ih[HR+d] + b_hh[HR+d]);
      const float hn = accHN[e][dq] + b_hh[2*HR+d];
      const float xn = accXN[e][dq] + b_ih[2*HR+d];
      float arg = xn + r*hn;
      arg = fminf(fmaxf(arg, -15.f), 15.f);
      const float t2 = __expf(2.0f*arg);
      const float n = (t2 - 1.0f) / (t2 + 1.0f);
      const float hold = FIRST ? 0.0f : b2f(h_in[(size_t)eg*HR + d]);
      const float hnew = (1.0f - z)*n + z*hold;
      hvp[dq] = f2b(hnew);
    }
    *reinterpret_cast<ushort4*>(&h_out[(size_t)eg*HR + d0 + tx*4]) = hv;
  }
}

// ---------------- attention scores + segment max ----------------
__launch_bounds__(256)
__global__ void score_kernel(const unsigned short* __restrict__ hT,
                             const float* __restrict__ attn,
                             const int* __restrict__ idx,
                             float* __restrict__ a_buf,
                             unsigned int* __restrict__ mmax)
{
  const int flat = blockIdx.x*256 + threadIdx.x;   // [0, E*8)
  const int e = flat >> 3, h = flat & 7;
  const unsigned short* hp = &hT[(size_t)e*HR + h*HID];
  const float* ap = &attn[h*HID];
  float acc = 0.f;
  #pragma unroll
  for (int k=0;k<HID;k+=4){
    const ushort4 hv = *reinterpret_cast<const ushort4*>(&hp[k]);
    const float4 av = *reinterpret_cast<const float4*>(&ap[k]);
    acc += b2f(hv.x)*av.x + b2f(hv.y)*av.y + b2f(hv.z)*av.z + b2f(hv.w)*av.w;
  }
  const float a = acc > 0.f ? acc : 0.01f*acc;
  a_buf[flat] = a;
  const int dst = idx[e*WALK + 3];
  union{float f; unsigned u;} x; x.f = a;
  const unsigned key = (x.u & 0x80000000u) ? ~x.u : (x.u | 0x80000000u);
  atomicMax(&mmax[dst*NHEAD + h], key);
}

// ---------------- exp(a-m) + segment sum ----------------
__launch_bounds__(256)
__global__ void ea_kernel(const int* __restrict__ idx,
                          float* __restrict__ a_buf,
                          const unsigned int* __restrict__ mmax,
                          float* __restrict__ ssum)
{
  const int flat = blockIdx.x*256 + threadIdx.x;
  const int e = flat >> 3, h = flat & 7;
  const int dst = idx[e*WALK + 3];
  const unsigned key = mmax[dst*NHEAD + h];
  union{float f; unsigned u;} x;
  x.u = (key & 0x80000000u) ? (key & 0x7FFFFFFFu) : ~key;
  const float ea = __expf(a_buf[flat] - x.f);
  a_buf[flat] = ea;
  atomicAdd(&ssum[dst*NHEAD + h], ea);
}

// ---------------- ft = segment_sum(eft * alpha) ----------------
__launch_bounds__(256)
__global__ void ft_kernel(const unsigned short* __restrict__ hT,
                          const int* __restrict__ idx,
                          const float* __restrict__ a_buf,
                          const float* __restrict__ ssum,
                          float* __restrict__ ft)
{
  const int flat = blockIdx.x*256 + threadIdx.x;  // [0, E*512)
  const int e = flat >> 9, c = flat & 511, h = c >> 6;
  const int dst = idx[e*WALK + 3];
  const float alpha = a_buf[e*NHEAD + h] / ssum[dst*NHEAD + h];
  atomicAdd(&ft[(size_t)dst*HR + c], b2f(hT[(size_t)e*HR + c]) * alpha);
}

// ---------------- out = (ft @ W_emb.T + b_emb) @ W_last.T + b_last ----------------
__launch_bounds__(256)
__global__ void out_kernel(const float* __restrict__ ft,
                           const float* __restrict__ W_emb,
                           const float* __restrict__ b_emb,
                           const float* __restrict__ W_last,
                           const float* __restrict__ b_last,
                           float* __restrict__ out)
{
  __shared__ float fs[4][HR];
  __shared__ float rs[4][HID];
  const int tid = threadIdx.x;
  const int node0 = blockIdx.x*4;
  #pragma unroll
  for (int j=0;j<2;++j){
    const int flat = j*256 + tid;     // [0,512) float4 units
    const int row = flat >> 7;
    const int k4 = (flat & 127) * 4;
    *reinterpret_cast<float4*>(&fs[row][k4]) =
      *reinterpret_cast<const float4*>(&ft[(size_t)(node0+row)*HR + k4]);
  }
  __syncthreads();
  const int nn = tid >> 6, c = tid & 63;
  float acc = b_emb[c];
  const float* wr = &W_emb[c*HR];
  #pragma unroll 8
  for (int k=0;k<HR;k+=4){
    const float4 w = *reinterpret_cast<const float4*>(&wr[k]);
    acc += fs[nn][k]*w.x + fs[nn][k+1]*w.y + fs[nn][k+2]*w.z + fs[nn][k+3]*w.w;
  }
  rs[nn][c] = acc;
  __syncthreads();
  if (tid < 64){
    const int n2 = tid >> 4, o = tid & 15;
    float oa = b_last[o];
    const float* wl = &W_last[o*HID];
    #pragma unroll
    for (int k=0;k<HID;++k) oa += rs[n2][k]*wl[k];
    out[(size_t)(node0+n2)*OUTD + o] = oa;
  }
}

// ---------------- launch ----------------
extern "C" void kernel_launch(void* const* d_in, const int* in_sizes, int n_in,
                              void* d_out, int out_size, void* d_ws, size_t ws_size,
                              hipStream_t stream)
{
  (void)in_sizes; (void)n_in; (void)out_size; (void)ws_size;
  const float* x      = (const float*)d_in[0];
  const float* W_mlp  = (const float*)d_in[1];
  const float* b_mlp  = (const float*)d_in[2];
  const float* W_ih   = (const float*)d_in[3];
  const float* W_hh   = (const float*)d_in[4];
  const float* b_ih   = (const float*)d_in[5];
  const float* b_hh   = (const float*)d_in[6];
  const float* attn   = (const float*)d_in[7];
  const float* W_emb  = (const float*)d_in[8];
  const float* b_emb  = (const float*)d_in[9];
  const float* W_last = (const float*)d_in[10];
  const float* b_last = (const float*)d_in[11];
  const int*   idx    = (const int*)d_in[12];
  float* out = (float*)d_out;

  char* ws = (char*)d_ws;
  float*          emb   = (float*)(ws + 0);                 //  5,120,000 B
  unsigned short* h_a   = (unsigned short*)(ws + 5120000);  //102,400,000 B
  unsigned short* h_b   = (unsigned short*)(ws + 107520000);//102,400,000 B
  float*          a_buf = (float*)(ws + 209920000);         //  3,200,000 B
  unsigned int*   mmax  = (unsigned int*)(ws + 213120000);  //    640,000 B
  float*          ssum  = (float*)(ws + 213760000);         //    640,000 B
  float*          ft    = (float*)(ws + 214400000);         // 40,960,000 B
  // total = 255,360,000 B

  // zero: mmax (0 == identity key for max), ssum, ft  (contiguous region)
  hipMemsetAsync(mmax, 0, 42240000, stream);

  emb_kernel<<<N_NODES/4, 256, 0, stream>>>(x, W_mlp, b_mlp, emb);

  dim3 ggrid(N_EDGES/32, 8);
  gru_kernel<true ><<<ggrid, 256, 0, stream>>>(emb, idx, h_a, h_a, W_ih, W_hh, b_ih, b_hh, 0);
  gru_kernel<false><<<ggrid, 256, 0, stream>>>(emb, idx, h_a, h_b, W_ih, W_hh, b_ih, b_hh, 1);
  gru_kernel<false><<<ggrid, 256, 0, stream>>>(emb, idx, h_b, h_a, W_ih, W_hh, b_ih, b_hh, 2);
  gru_kernel<false><<<ggrid, 256, 0, stream>>>(emb, idx, h_a, h_b, W_ih, W_hh, b_ih, b_hh, 3);
  // final hT lives in h_b

  score_kernel<<<N_EDGES*NHEAD/256, 256, 0, stream>>>(h_b, attn, idx, a_buf, mmax);
  ea_kernel<<<N_EDGES*NHEAD/256, 256, 0, stream>>>(idx, a_buf, mmax, ssum);
  ft_kernel<<<(N_EDGES*HR)/256, 256, 0, stream>>>(h_b, idx, a_buf, ssum, ft);
  out_kernel<<<N_NODES/4, 256, 0, stream>>>(ft, W_emb, b_emb, W_last, b_last, out);
}

// Round 2
// 1697.758 us; speedup vs baseline: 12.2525x; 12.2525x over previous
//
#include <hip/hip_runtime.h>
#include <hip/hip_bf16.h>
#include <cstdint>

#define N_NODES 20000
#define N_EDGES 100000
#define WALK 4
#define FDIM 256
#define HID 64
#define NHEAD 8
#define HR 512
#define OUTD 16

typedef __attribute__((ext_vector_type(8))) short bf16x8;
typedef __attribute__((ext_vector_type(4))) float f32x4;

__device__ __forceinline__ float b2f(unsigned short u){
  union{float f; unsigned u;} x; x.u = ((unsigned)u)<<16; return x.f;
}
__device__ __forceinline__ unsigned short f2b(float f){
  union{float f; unsigned u;} x; x.f = f;
  unsigned r = x.u + 0x7FFFu + ((x.u>>16)&1u);
  return (unsigned short)(r>>16);
}
__device__ __forceinline__ float sigmoidf_(float v){ return 1.0f/(1.0f+__expf(-v)); }

__device__ __forceinline__ void gload16(const void* g, void* l){
  __builtin_amdgcn_global_load_lds(
      (const __attribute__((address_space(1))) void*)(g),
      (__attribute__((address_space(3))) void*)(l),
      16, 0, 0);
}

__device__ __forceinline__ f32x4 mfma16(bf16x8 a, bf16x8 b, f32x4 c){
  return __builtin_amdgcn_mfma_f32_16x16x32_bf16(a, b, c, 0, 0, 0);
}

// swizzled h address: chunk (16B = 8 bf16) index XORed with (e&7) within each 64-col group
__device__ __forceinline__ size_t haddr_swz(int e, int d){
  const int cidx = (d >> 3) & 7;
  const int o = d & 7;
  return (size_t)e*HR + (d & 448) + (((cidx ^ (e & 7)) << 3) | o);
}
__device__ __forceinline__ size_t haddr_lin(int e, int d){
  return (size_t)e*HR + d;
}

// ---------------- emb = bf16(x @ W_mlp.T + b_mlp)  (20000x64) ----------------
__launch_bounds__(256)
__global__ void emb_kernel(const float* __restrict__ x,
                           const float* __restrict__ Wm,
                           const float* __restrict__ bm,
                           unsigned short* __restrict__ emb_bf)
{
  __shared__ float xs[4][FDIM];
  const int tid = threadIdx.x;
  const int node0 = blockIdx.x * 4;
  {
    const int row = tid >> 6;
    const int k4  = (tid & 63) * 4;
    *reinterpret_cast<float4*>(&xs[row][k4]) =
      *reinterpret_cast<const float4*>(&x[(size_t)(node0+row)*FDIM + k4]);
  }
  __syncthreads();
  const int nn = tid >> 6, c = tid & 63;
  float acc = bm[c];
  const float* wr = &Wm[c*FDIM];
  #pragma unroll 8
  for (int k=0;k<FDIM;k+=4){
    const float4 w = *reinterpret_cast<const float4*>(&wr[k]);
    acc += xs[nn][k]*w.x + xs[nn][k+1]*w.y + xs[nn][k+2]*w.z + xs[nn][k+3]*w.w;
  }
  emb_bf[(size_t)(node0+nn)*HID + c] = f2b(acc);
}

// ---------------- weight prep: bf16, gate-block reorder, chunk-swizzle ----------------
// WhhP: [8 dblocks][192 rows][512 k]  row r -> W_hh row g=(r>>6)*512 + db*64 + (r&63)
//   content at k-position (group kg, chunk c, o) = W[g][kg*64 + ((c^(r&7))<<3) + o]
// WihP: [8][192][64] analogous from W_ih
__launch_bounds__(256)
__global__ void prep_kernel(const float* __restrict__ Whh,
                            const float* __restrict__ Wih,
                            unsigned short* __restrict__ WhhP,
                            unsigned short* __restrict__ WihP)
{
  const int t = blockIdx.x*256 + threadIdx.x;
  if (t < 8*192*512){
    const int k = t & 511;
    const int r = (t >> 9) % 192;
    const int db = t / 98304;
    const int g = (r>>6)*HR + db*64 + (r&63);
    const int kg = k >> 6, kw = k & 63;
    const int c = kw >> 3, o = kw & 7;
    const int ksrc = (kg<<6) + (((c ^ (r&7)) << 3) | o);
    WhhP[t] = f2b(Whh[(size_t)g*HR + ksrc]);
  }
  if (t < 8*192*64){
    const int k = t & 63;
    const int r = (t >> 6) % 192;
    const int db = t / 12288;
    const int g = (r>>6)*HR + db*64 + (r&63);
    const int c = k >> 3, o = k & 7;
    const int ksrc = ((c ^ (r&7)) << 3) | o;
    WihP[t] = f2b(Wih[(size_t)g*HID + ksrc]);
  }
}

// ---------------- GRU step via MFMA ----------------
// Tile: 128 edges x 192 cols (= gates r,z,n for one 64-wide d-block).
// K: 8 steps of 64 over h (bf16, swizzled layout), + 1 step of 64 over gathered emb.
// 4 waves; wave w owns rows [w*32, w*32+32) (2 M-frags), all 12 N-frags.
template<bool FIRST, bool SWZ_OUT>
__launch_bounds__(256)
__global__ void gru_mfma(const unsigned short* __restrict__ emb_bf,
                         const int* __restrict__ idx,
                         const unsigned short* __restrict__ h_in,
                         unsigned short* __restrict__ h_out,
                         const unsigned short* __restrict__ WhhP,
                         const unsigned short* __restrict__ WihP,
                         const float* __restrict__ b_ih,
                         const float* __restrict__ b_hh,
                         int step)
{
  __shared__ __align__(16) unsigned short As[128*64];   // 16 KB
  __shared__ __align__(16) unsigned short Bs[192*64];   // 24 KB

  const int tid = threadIdx.x;
  const int lane = tid & 63;
  const int w = tid >> 6;

  // bijective XCD swizzle: 6256 = 8*782; consecutive sid within an XCD chunk
  // cover the 8 d-blocks of one edge-tile -> h tile read once per XCD L2.
  const int bid = blockIdx.x;
  const int sid = (bid & 7) * 782 + (bid >> 3);
  const int et = sid >> 3;
  const int db = sid & 7;
  const int e0 = et * 128;

  f32x4 accR[2][4], accZ[2][4], accNh[2][4], accNx[2][4];
  #pragma unroll
  for (int m=0;m<2;++m)
    #pragma unroll
    for (int f=0;f<4;++f){
      accR[m][f] = (f32x4)(0.f); accZ[m][f] = (f32x4)(0.f);
      accNh[m][f] = (f32x4)(0.f); accNx[m][f] = (f32x4)(0.f);
    }

  auto stageA_h = [&](int k0){
    #pragma unroll
    for (int j=0;j<4;++j){
      const int flat = (w*4+j)*64 + lane;
      const int r = flat >> 3, c = flat & 7;
      int e = e0 + r; if (e >= N_EDGES) e = N_EDGES-1;
      gload16(h_in + ((size_t)e*HR + k0 + c*8), (char*)As + (w*4+j)*1024);
    }
  };
  auto stageB_h = [&](int k0){
    #pragma unroll
    for (int j=0;j<6;++j){
      const int flat = j*256 + tid;
      const int r = flat >> 3, c = flat & 7;
      gload16(WhhP + ((size_t)(db*192 + r)*HR + k0 + c*8),
              (char*)Bs + (j*256 + w*64)*16);
    }
  };
  auto stageA_x = [&](){
    #pragma unroll
    for (int j=0;j<4;++j){
      const int flat = (w*4+j)*64 + lane;
      const int r = flat >> 3, c = flat & 7;
      int e = e0 + r; if (e >= N_EDGES) e = N_EDGES-1;
      const int node = idx[e*WALK + step];
      gload16(emb_bf + ((size_t)node*HID + ((c ^ (r&7)) << 3)),
              (char*)As + (w*4+j)*1024);
    }
  };
  auto stageB_x = [&](){
    #pragma unroll
    for (int j=0;j<6;++j){
      const int flat = j*256 + tid;
      const int r = flat >> 3, c = flat & 7;
      gload16(WihP + ((size_t)(db*192 + r)*HID + c*8),
              (char*)Bs + (j*256 + w*64)*16);
    }
  };

  auto readA = [&](int row, int kk)->bf16x8{
    const int chunk = (kk<<2) + (lane>>4);
    const int byte = (row<<7) + ((chunk ^ (row&7))<<4);
    return *reinterpret_cast<const bf16x8*>(reinterpret_cast<const char*>(As) + byte);
  };
  auto readB = [&](int row, int kk)->bf16x8{
    const int chunk = (kk<<2) + (lane>>4);
    const int byte = (row<<7) + ((chunk ^ (row&7))<<4);
    return *reinterpret_cast<const bf16x8*>(reinterpret_cast<const char*>(Bs) + byte);
  };

  auto computeTile = [&](bool xs){
    const int ar = lane & 15;
    #pragma unroll
    for (int kk=0; kk<2; ++kk){
      const bf16x8 a0 = readA(w*32 + ar, kk);
      const bf16x8 a1 = readA(w*32 + 16 + ar, kk);
      #pragma unroll
      for (int f=0; f<4; ++f){
        const bf16x8 b = readB(f*16 + ar, kk);
        accR[0][f] = mfma16(a0, b, accR[0][f]);
        accR[1][f] = mfma16(a1, b, accR[1][f]);
      }
      #pragma unroll
      for (int f=0; f<4; ++f){
        const bf16x8 b = readB((f+4)*16 + ar, kk);
        accZ[0][f] = mfma16(a0, b, accZ[0][f]);
        accZ[1][f] = mfma16(a1, b, accZ[1][f]);
      }
      if (!xs){
        #pragma unroll
        for (int f=0; f<4; ++f){
          const bf16x8 b = readB((f+8)*16 + ar, kk);
          accNh[0][f] = mfma16(a0, b, accNh[0][f]);
          accNh[1][f] = mfma16(a1, b, accNh[1][f]);
        }
      } else {
        #pragma unroll
        for (int f=0; f<4; ++f){
          const bf16x8 b = readB((f+8)*16 + ar, kk);
          accNx[0][f] = mfma16(a0, b, accNx[0][f]);
          accNx[1][f] = mfma16(a1, b, accNx[1][f]);
        }
      }
    }
  };

  const int NT = FIRST ? 1 : 9;
  if (FIRST){ stageA_x(); stageB_x(); }
  else      { stageA_h(0); stageB_h(0); }

  for (int t=0; t<NT; ++t){
    __syncthreads();
    if (t == NT-1) computeTile(true);
    else           computeTile(false);
    if (t+1 < NT){
      __syncthreads();
      if (t+1 == NT-1){ stageA_x(); stageB_x(); }
      else            { stageA_h((t+1)*64); stageB_h((t+1)*64); }
    }
  }

  // ---- epilogue: gates + h update ----
  #pragma unroll
  for (int fr=0; fr<4; ++fr){
    const int d = db*64 + fr*16 + (lane & 15);
    const float bir = b_ih[d],        bhr = b_hh[d];
    const float biz = b_ih[HR+d],     bhz = b_hh[HR+d];
    const float bin_ = b_ih[2*HR+d],  bhn = b_hh[2*HR+d];
    #pragma unroll
    for (int m=0;m<2;++m){
      #pragma unroll
      for (int reg=0; reg<4; ++reg){
        const int row = w*32 + m*16 + ((lane>>4)<<2) + reg;
        const int e = e0 + row;
        if (e < N_EDGES){
          const float r = sigmoidf_(accR[m][fr][reg] + bir + bhr);
          const float z = sigmoidf_(accZ[m][fr][reg] + biz + bhz);
          const float hn = accNh[m][fr][reg] + bhn;
          const float xn = accNx[m][fr][reg] + bin_;
          float arg = xn + r*hn;
          arg = fminf(fmaxf(arg, -15.f), 15.f);
          const float t2 = __expf(2.0f*arg);
          const float n = (t2 - 1.0f) / (t2 + 1.0f);
          const float hold = FIRST ? 0.0f : b2f(h_in[haddr_swz(e, d)]);
          const float hv = (1.0f - z)*n + z*hold;
          if (SWZ_OUT) h_out[haddr_swz(e, d)] = f2b(hv);
          else         h_out[haddr_lin(e, d)] = f2b(hv);
        }
      }
    }
  }
}

// ---------------- attention scores + segment max ----------------
__launch_bounds__(256)
__global__ void score_kernel(const unsigned short* __restrict__ hT,
                             const float* __restrict__ attn,
                             const int* __restrict__ idx,
                             float* __restrict__ a_buf,
                             unsigned int* __restrict__ mmax)
{
  const int flat = blockIdx.x*256 + threadIdx.x;   // [0, E*8)
  const int e = flat >> 3, h = flat & 7;
  const unsigned short* hp = &hT[(size_t)e*HR + h*HID];
  const float* ap = &attn[h*HID];
  float acc = 0.f;
  #pragma unroll
  for (int k=0;k<HID;k+=4){
    const ushort4 hv = *reinterpret_cast<const ushort4*>(&hp[k]);
    const float4 av = *reinterpret_cast<const float4*>(&ap[k]);
    acc += b2f(hv.x)*av.x + b2f(hv.y)*av.y + b2f(hv.z)*av.z + b2f(hv.w)*av.w;
  }
  const float a = acc > 0.f ? acc : 0.01f*acc;
  a_buf[flat] = a;
  const int dst = idx[e*WALK + 3];
  union{float f; unsigned u;} x; x.f = a;
  const unsigned key = (x.u & 0x80000000u) ? ~x.u : (x.u | 0x80000000u);
  atomicMax(&mmax[dst*NHEAD + h], key);
}

// ---------------- exp(a-m) + segment sum ----------------
__launch_bounds__(256)
__global__ void ea_kernel(const int* __restrict__ idx,
                          float* __restrict__ a_buf,
                          const unsigned int* __restrict__ mmax,
                          float* __restrict__ ssum)
{
  const int flat = blockIdx.x*256 + threadIdx.x;
  const int e = flat >> 3, h = flat & 7;
  const int dst = idx[e*WALK + 3];
  const unsigned key = mmax[dst*NHEAD + h];
  union{float f; unsigned u;} x;
  x.u = (key & 0x80000000u) ? (key & 0x7FFFFFFFu) : ~key;
  const float ea = __expf(a_buf[flat] - x.f);
  a_buf[flat] = ea;
  atomicAdd(&ssum[dst*NHEAD + h], ea);
}

// ---------------- ft = segment_sum(eft * alpha) ----------------
__launch_bounds__(256)
__global__ void ft_kernel(const unsigned short* __restrict__ hT,
                          const int* __restrict__ idx,
                          const float* __restrict__ a_buf,
                          const float* __restrict__ ssum,
                          float* __restrict__ ft)
{
  const int flat = blockIdx.x*256 + threadIdx.x;  // [0, E*512)
  const int e = flat >> 9, c = flat & 511, h = c >> 6;
  const int dst = idx[e*WALK + 3];
  const float alpha = a_buf[e*NHEAD + h] / ssum[dst*NHEAD + h];
  atomicAdd(&ft[(size_t)dst*HR + c], b2f(hT[(size_t)e*HR + c]) * alpha);
}

// ---------------- out = (ft @ W_emb.T + b_emb) @ W_last.T + b_last ----------------
__launch_bounds__(256)
__global__ void out_kernel(const float* __restrict__ ft,
                           const float* __restrict__ W_emb,
                           const float* __restrict__ b_emb,
                           const float* __restrict__ W_last,
                           const float* __restrict__ b_last,
                           float* __restrict__ out)
{
  __shared__ float fs[4][HR];
  __shared__ float rs[4][HID];
  const int tid = threadIdx.x;
  const int node0 = blockIdx.x*4;
  #pragma unroll
  for (int j=0;j<2;++j){
    const int flat = j*256 + tid;
    const int row = flat >> 7;
    const int k4 = (flat & 127) * 4;
    *reinterpret_cast<float4*>(&fs[row][k4]) =
      *reinterpret_cast<const float4*>(&ft[(size_t)(node0+row)*HR + k4]);
  }
  __syncthreads();
  const int nn = tid >> 6, c = tid & 63;
  float acc = b_emb[c];
  const float* wr = &W_emb[c*HR];
  #pragma unroll 8
  for (int k=0;k<HR;k+=4){
    const float4 w = *reinterpret_cast<const float4*>(&wr[k]);
    acc += fs[nn][k]*w.x + fs[nn][k+1]*w.y + fs[nn][k+2]*w.z + fs[nn][k+3]*w.w;
  }
  rs[nn][c] = acc;
  __syncthreads();
  if (tid < 64){
    const int n2 = tid >> 4, o = tid & 15;
    float oa = b_last[o];
    const float* wl = &W_last[o*HID];
    #pragma unroll
    for (int k=0;k<HID;++k) oa += rs[n2][k]*wl[k];
    out[(size_t)(node0+n2)*OUTD + o] = oa;
  }
}

// ---------------- launch ----------------
extern "C" void kernel_launch(void* const* d_in, const int* in_sizes, int n_in,
                              void* d_out, int out_size, void* d_ws, size_t ws_size,
                              hipStream_t stream)
{
  (void)in_sizes; (void)n_in; (void)out_size; (void)ws_size;
  const float* x      = (const float*)d_in[0];
  const float* W_mlp  = (const float*)d_in[1];
  const float* b_mlp  = (const float*)d_in[2];
  const float* W_ih   = (const float*)d_in[3];
  const float* W_hh   = (const float*)d_in[4];
  const float* b_ih   = (const float*)d_in[5];
  const float* b_hh   = (const float*)d_in[6];
  const float* attn   = (const float*)d_in[7];
  const float* W_emb  = (const float*)d_in[8];
  const float* b_emb  = (const float*)d_in[9];
  const float* W_last = (const float*)d_in[10];
  const float* b_last = (const float*)d_in[11];
  const int*   idx    = (const int*)d_in[12];
  float* out = (float*)d_out;

  char* ws = (char*)d_ws;
  unsigned short* emb_bf = (unsigned short*)(ws + 0);           //   2,560,000
  unsigned short* WhhP   = (unsigned short*)(ws + 2560000);     //   1,572,864
  unsigned short* WihP   = (unsigned short*)(ws + 4132864);     //     196,608
  unsigned short* h_a    = (unsigned short*)(ws + 4329472);     // 102,400,000
  unsigned short* h_b    = (unsigned short*)(ws + 106729472);   // 102,400,000
  float*          a_buf  = (float*)(ws + 209129472);            //   3,200,000
  unsigned int*   mmax   = (unsigned int*)(ws + 212329472);     //     640,000
  float*          ssum   = (float*)(ws + 212969472);            //     640,000
  float*          ft     = (float*)(ws + 213609472);            //  40,960,000
  // total = 254,569,472 B

  hipMemsetAsync(mmax, 0, 42240000, stream);   // mmax + ssum + ft

  prep_kernel<<<3072, 256, 0, stream>>>(W_hh, W_ih, WhhP, WihP);
  emb_kernel<<<N_NODES/4, 256, 0, stream>>>(x, W_mlp, b_mlp, emb_bf);

  const int NWG = 782*8;  // 6256, %8==0 -> bijective XCD swizzle
  gru_mfma<true,  true ><<<NWG, 256, 0, stream>>>(emb_bf, idx, h_a, h_a, WhhP, WihP, b_ih, b_hh, 0);
  gru_mfma<false, true ><<<NWG, 256, 0, stream>>>(emb_bf, idx, h_a, h_b, WhhP, WihP, b_ih, b_hh, 1);
  gru_mfma<false, true ><<<NWG, 256, 0, stream>>>(emb_bf, idx, h_b, h_a, WhhP, WihP, b_ih, b_hh, 2);
  gru_mfma<false, false><<<NWG, 256, 0, stream>>>(emb_bf, idx, h_a, h_b, WhhP, WihP, b_ih, b_hh, 3);
  // final hT (linear layout) lives in h_b

  score_kernel<<<N_EDGES*NHEAD/256, 256, 0, stream>>>(h_b, attn, idx, a_buf, mmax);
  ea_kernel<<<N_EDGES*NHEAD/256, 256, 0, stream>>>(idx, a_buf, mmax, ssum);
  ft_kernel<<<(N_EDGES*HR)/256, 256, 0, stream>>>(h_b, idx, a_buf, ssum, ft);
  out_kernel<<<N_NODES/4, 256, 0, stream>>>(ft, W_emb, b_emb, W_last, b_last, out);
}